// Round 6
// baseline (187.515 us; speedup 1.0000x reference)
//
#include <hip/hip_runtime.h>
#include <math.h>

#define N_PTS 65536
#define M_IND 1024
#define KNN 16
#define JITTER 1e-4f

// Packed lower-triangular Su: P[i*(i+1)/2 + j], j <= i.
#define PACKED_FLOATS (M_IND * (M_IND + 1) / 2)               // 524800
#define PACKED_BYTES  ((size_t)PACKED_FLOATS * sizeof(float)) // 2,099,200 B

#define TSU 32
#define SU_BLOCKS 528          // 32*33/2 triangular tiles
#define PTS_PER_BLK 128        // MODE0 fallback shape
#define QSTRIDE 17             // u64 per point row (MODE0 fallback)
#define GRID_BLKS (N_PTS / PTS_PER_BLK)   // 512

// R16 ledger:
//  - R14/R15 ground truth: sel+su=76.5us standalone; p2 ~45us dominated by the
//    REDUNDANT serial Cholesky (qs-split was a no-op); selection TLP capped at
//    2 waves/SIMD by the 4-sub x 2-pt decomposition.
//  - R16: (a) oct-selection (8 subs x 128 cands, 2 pts/thread) -> 2x threads,
//    same LDS-instr total; (b) cooperative 4-lane phase 2 (L row-cyclic,
//    static-indexed, ~100 live regs) -> fits (256,4), 4 blk/CU, and 1/4 the
//    per-lane Cholesky/solve work; (c) su_kernel + selp2_kernel split: kernel
//    boundary is the sync, NO spin, NO co-residency constraint.
//  - Spill tripwire: WRITE_SIZE must stay ~3 MB. R11/R12: forcing min-waves
//    on a ~200-reg serial phase 2 spills catastrophically; R16 avoids it by
//    SHRINKING the live set, not squeezing the allocator.

// ---------------------------------------------------------------------------
// One 32x32 Su tile (packed tril(Lu Lu^T)). As/Bs are LDS scratch.
// ---------------------------------------------------------------------------
__device__ __forceinline__ void su_tile(const float* __restrict__ Lu_raw,
                                        float* __restrict__ P,
                                        int bid, int tid,
                                        float (*As)[36], float (*Bs)[36]) {
    int rt = (int)((sqrtf(8.0f * (float)bid + 1.0f) - 1.0f) * 0.5f);
    while ((rt + 1) * (rt + 2) / 2 <= bid) ++rt;
    while (rt * (rt + 1) / 2 > bid) --rt;
    int ct = bid - rt * (rt + 1) / 2;   // ct <= rt
    int i0 = rt * TSU, j0 = ct * TSU;

    int tx = tid & 15, ty = tid >> 4;
    int sr = tid >> 3, sc = (tid & 7) << 2;
    float a00 = 0.f, a01 = 0.f, a10 = 0.f, a11 = 0.f;

    int nch = ct + 1;                      // k-chunks of 32 (k <= j0+31)
    int gi = i0 + sr, gj = j0 + sr;
    float4 pa = *(const float4*)(Lu_raw + (unsigned)gi * M_IND + sc);
    float4 pb = *(const float4*)(Lu_raw + (unsigned)gj * M_IND + sc);

    for (int c = 0; c < nch; ++c) {
        int gk = (c << 5) + sc;
        float aa[4] = {pa.x, pa.y, pa.z, pa.w};
        float bb[4] = {pb.x, pb.y, pb.z, pb.w};
        #pragma unroll
        for (int q = 0; q < 4; ++q) {
            int k = gk + q;
            aa[q] = (k < gi) ? aa[q] : ((k == gi) ? __expf(aa[q]) : 0.0f);
            bb[q] = (k < gj) ? bb[q] : ((k == gj) ? __expf(bb[q]) : 0.0f);
        }
        *(float4*)&As[sr][sc] = make_float4(aa[0], aa[1], aa[2], aa[3]);
        *(float4*)&Bs[sr][sc] = make_float4(bb[0], bb[1], bb[2], bb[3]);
        __syncthreads();
        if (c + 1 < nch) {
            int kn = ((c + 1) << 5) + sc;
            pa = *(const float4*)(Lu_raw + (unsigned)gi * M_IND + kn);
            pb = *(const float4*)(Lu_raw + (unsigned)gj * M_IND + kn);
        }
        #pragma unroll
        for (int kk = 0; kk < 32; kk += 4) {
            float4 av0 = *(const float4*)&As[ty][kk];
            float4 av1 = *(const float4*)&As[ty + 16][kk];
            float4 bv0 = *(const float4*)&Bs[tx][kk];
            float4 bv1 = *(const float4*)&Bs[tx + 16][kk];
            a00 = fmaf(av0.x, bv0.x, fmaf(av0.y, bv0.y, fmaf(av0.z, bv0.z, fmaf(av0.w, bv0.w, a00))));
            a01 = fmaf(av0.x, bv1.x, fmaf(av0.y, bv1.y, fmaf(av0.z, bv1.z, fmaf(av0.w, bv1.w, a01))));
            a10 = fmaf(av1.x, bv0.x, fmaf(av1.y, bv0.y, fmaf(av1.z, bv0.z, fmaf(av1.w, bv0.w, a10))));
            a11 = fmaf(av1.x, bv1.x, fmaf(av1.y, bv1.y, fmaf(av1.z, bv1.z, fmaf(av1.w, bv1.w, a11))));
        }
        __syncthreads();
    }

    int ia = i0 + ty, ib = i0 + ty + 16;
    int ja = j0 + tx, jb = j0 + tx + 16;
    if (ja <= ia) P[((unsigned)ia * (ia + 1) >> 1) + ja] = a00;
    if (jb <= ia) P[((unsigned)ia * (ia + 1) >> 1) + jb] = a01;
    if (ja <= ib) P[((unsigned)ib * (ib + 1) >> 1) + ja] = a10;
    if (jb <= ib) P[((unsigned)ib * (ib + 1) >> 1) + jb] = a11;
}

__global__ __launch_bounds__(256) void su_kernel(const float* __restrict__ Lu_raw,
                                                 float* __restrict__ P) {
    __shared__ float As[TSU][36];
    __shared__ float Bs[TSU][36];
    su_tile(Lu_raw, P, blockIdx.x, threadIdx.x, As, Bs);
}

// ---------------------------------------------------------------------------
// Sorting-network helpers.
// ---------------------------------------------------------------------------
__device__ __forceinline__ void ce(unsigned long long& x, unsigned long long& y) {
    unsigned long long a = x, b = y;
    bool c = a < b;
    x = c ? a : b;
    y = c ? b : a;
}
__device__ __forceinline__ void ce(float& x, float& y) {
    float a = fminf(x, y), b = fmaxf(x, y);
    x = a; y = b;
}

template <typename KT>
__device__ __forceinline__ void sort16(KT* a) {
    #pragma unroll
    for (int p = 1; p < 16; p <<= 1)
        #pragma unroll
        for (int k = p; k >= 1; k >>= 1)
            #pragma unroll
            for (int j = k & (p - 1); j + k < 16; j += 2 * k)
                #pragma unroll
                for (int i = 0; i < k; ++i)
                    if (i + j + k < 16)
                        if (((i + j) / (2 * p)) == ((i + j + k) / (2 * p)))
                            ce(a[i + j], a[i + j + k]);
}

template <typename KT>
__device__ __forceinline__ void cleanup16(KT* a) {
    #pragma unroll
    for (int d = 8; d >= 1; d >>= 1)
        #pragma unroll
        for (int i = 0; i < 16; ++i)
            if ((i & d) == 0) ce(a[i], a[i | d]);
}

// u-space distance surrogate: u = 0.5*|z|^2 - x.z  (Zs.w holds 0.5*|z|^2).
// d = max(2u + xq, 0) is monotone in u.
__device__ __forceinline__ float uval(float4 z, float xn0, float xn1, float xn2) {
    return fmaf(xn0, z.x, fmaf(xn1, z.y, fmaf(xn2, z.z, z.w)));
}

// Static-index accessors for the row-cyclic L storage (lane l owns rows
// l, l+4, l+8, l+12; Lk[] holds row l+4k, valid cols 0..l+4k-1 <= 4k+2).
// Index clamps keep dead unrolled branches in-bounds (rule: no OOB even in
// dead code). Always used under the static guard (c) < 4*(k+1).
#define LI0(c) ((c) & 3)
#define LI1(c) ((c) & 7)
#define LI2(c) ((c) < 12 ? (c) : 0)

// ---------------------------------------------------------------------------
// SELP2: selection (oct: 8 subs x 128 cands, 2 pts/thread) + cooperative
// 4-lane phase 2. 1024 blocks x 256 thr, 64 pts/block, launch_bounds(256,4).
// LDS: Zs 16384 | mus 4096 | qb 16384 (64 pts x 256 B: myc u16[128] then
// reused as keys u64[32]) = 36864 B -> 4 blocks/CU by LDS.
// ---------------------------------------------------------------------------
__global__ __launch_bounds__(256, 4) void selp2_kernel(const float* __restrict__ X,
                                                       const float* __restrict__ Z,
                                                       const float* __restrict__ mu,
                                                       const float* __restrict__ P,
                                                       float* __restrict__ out) {
    __shared__ __align__(16) char smem[36864];
    float4* Zs = (float4*)smem;                                   // 16384 B
    float* mus = (float*)(smem + 16384);                          // 4096 B
    unsigned long long* qb = (unsigned long long*)(smem + 20480); // 16384 B
    int tid = threadIdx.x;

    for (int r = tid; r < M_IND; r += 256) {
        float zx = Z[r * 3 + 0], zy = Z[r * 3 + 1], zz = Z[r * 3 + 2];
        Zs[r] = make_float4(zx, zy, zz, 0.5f * (zx * zx + zy * zy + zz * zz));
        mus[r] = mu[r];
    }
    __syncthreads();

    // ===================== SELECTION (oct decomposition) ====================
    {
        int oct = tid >> 3, sub = tid & 7;   // oct 0..31; pair (oct, oct+32)
        int nA = blockIdx.x * 64 + oct;
        int nB = nA + 32;
        float xA0 = X[nA * 3 + 0], xA1 = X[nA * 3 + 1], xA2 = X[nA * 3 + 2];
        float xB0 = X[nB * 3 + 0], xB1 = X[nB * 3 + 1], xB2 = X[nB * 3 + 2];
        float xqA = fmaf(xA0, xA0, fmaf(xA1, xA1, xA2 * xA2));
        float xqB = fmaf(xB0, xB0, fmaf(xB1, xB1, xB2 * xB2));
        float mA0 = -xA0, mA1 = -xA1, mA2 = -xA2;
        float mB0 = -xB0, mB1 = -xB1, mB2 = -xB2;
        int mbase = sub << 7;                // 128 candidates per sub
        int rot = sub << 1;                  // spread subs across banks

        // ---- Pass 1: 16 class minima (classes of 8) per point, u-space ----
        float TA[16], TB[16];
        #pragma unroll
        for (int j = 0; j < 16; ++j) { TA[j] = 3.4e38f; TB[j] = 3.4e38f; }
        #pragma unroll 1
        for (int c = 0; c < 8; ++c) {
            int base = mbase + (c << 4);
            #pragma unroll
            for (int j = 0; j < 16; ++j) {
                int m = base + ((j + rot) & 15);
                float4 z = Zs[m];
                TA[j] = fminf(TA[j], uval(z, mA0, mA1, mA2));
                TB[j] = fminf(TB[j], uval(z, mB0, mB1, mB2));
            }
        }
        sort16(TA);
        sort16(TB);
        #pragma unroll
        for (int round = 1; round <= 4; round <<= 1) {   // merge across 8 subs
            float oA[16], oB[16];
            #pragma unroll
            for (int i = 0; i < 16; ++i) {
                oA[i] = __shfl_xor(TA[i], round, 64);
                oB[i] = __shfl_xor(TB[i], round, 64);
            }
            #pragma unroll
            for (int i = 0; i < 16; ++i) {
                TA[i] = fminf(TA[i], oA[15 - i]);
                TB[i] = fminf(TB[i], oB[15 - i]);
            }
            cleanup16(TA);
            cleanup16(TB);
        }
        float TstarA = TA[15], TstarB = TB[15];

        // ---- Pass 2: collect indices with u <= Tstar (u16, cap 16/sub) ----
        unsigned short* mycA = ((unsigned short*)qb) + oct * 128 + sub * 16;
        unsigned short* mycB = ((unsigned short*)qb) + (oct + 32) * 128 + sub * 16;
        int cntA = 0, cntB = 0;
        #pragma unroll 1
        for (int c = 0; c < 8; ++c) {
            int base = mbase + (c << 4);
            #pragma unroll
            for (int j = 0; j < 16; ++j) {
                int m = base + ((j + rot) & 15);
                float4 z = Zs[m];
                float uA = uval(z, mA0, mA1, mA2);
                float uB = uval(z, mB0, mB1, mB2);
                if (uA <= TstarA) { if (cntA < 16) mycA[cntA] = (unsigned short)m; ++cntA; }
                if (uB <= TstarB) { if (cntB < 16) mycB[cntB] = (unsigned short)m; ++cntB; }
            }
        }

        int ovfA = cntA > 16 ? 1 : 0;
        ovfA |= __shfl_xor(ovfA, 1, 64);
        ovfA |= __shfl_xor(ovfA, 2, 64);
        ovfA |= __shfl_xor(ovfA, 4, 64);
        int ovfB = cntB > 16 ? 1 : 0;
        ovfB |= __shfl_xor(ovfB, 1, 64);
        ovfB |= __shfl_xor(ovfB, 2, 64);
        ovfB |= __shfl_xor(ovfB, 4, 64);

        // ---- finalize point A (keys overwrite A's own myc area) ----
        if (!ovfA) {
            const unsigned long long* m64 = (const unsigned long long*)mycA;
            unsigned long long raw[4] = {m64[0], m64[1], m64[2], m64[3]};
            unsigned long long C[16];
            #pragma unroll
            for (int i = 0; i < 16; ++i) {
                int m = (int)((raw[i >> 2] >> ((i & 3) * 16)) & 0x3FF);
                float u = uval(Zs[m], mA0, mA1, mA2);
                float d = fmaxf(fmaf(2.0f, u, xqA), 0.0f);
                unsigned long long key =
                    ((unsigned long long)__float_as_uint(d) << 32) | (unsigned)m;
                C[i] = (i < cntA) ? key : ~0ULL;
            }
            sort16(C);
            #pragma unroll
            for (int round = 1; round <= 4; round <<= 1) {
                unsigned long long o[16];
                #pragma unroll
                for (int i = 0; i < 16; ++i) o[i] = __shfl_xor(C[i], round, 64);
                #pragma unroll
                for (int i = 0; i < 16; ++i) {
                    unsigned long long b = o[15 - i];
                    C[i] = C[i] < b ? C[i] : b;
                }
                cleanup16(C);
            }
            if (sub == 0) {
                #pragma unroll
                for (int i = 0; i < 16; ++i) qb[oct * 32 + i] = C[i];
            }
        } else if (sub == 0) {
            unsigned long long R[16];
            #pragma unroll
            for (int i = 0; i < 16; ++i) R[i] = ~0ULL;
            for (int m = 0; m < M_IND; ++m) {
                float u = uval(Zs[m], mA0, mA1, mA2);
                float d = fmaxf(fmaf(2.0f, u, xqA), 0.0f);
                unsigned long long kk =
                    ((unsigned long long)__float_as_uint(d) << 32) | (unsigned)m;
                if (kk < R[15]) {
                    #pragma unroll
                    for (int j = 0; j < 16; ++j) {
                        unsigned long long t = R[j];
                        bool cc = kk < t;
                        R[j] = cc ? kk : t;
                        kk = cc ? t : kk;
                    }
                }
            }
            #pragma unroll
            for (int i = 0; i < 16; ++i) qb[oct * 32 + i] = R[i];
        }

        // ---- finalize point B ----
        if (!ovfB) {
            const unsigned long long* m64 = (const unsigned long long*)mycB;
            unsigned long long raw[4] = {m64[0], m64[1], m64[2], m64[3]};
            unsigned long long C[16];
            #pragma unroll
            for (int i = 0; i < 16; ++i) {
                int m = (int)((raw[i >> 2] >> ((i & 3) * 16)) & 0x3FF);
                float u = uval(Zs[m], mB0, mB1, mB2);
                float d = fmaxf(fmaf(2.0f, u, xqB), 0.0f);
                unsigned long long key =
                    ((unsigned long long)__float_as_uint(d) << 32) | (unsigned)m;
                C[i] = (i < cntB) ? key : ~0ULL;
            }
            sort16(C);
            #pragma unroll
            for (int round = 1; round <= 4; round <<= 1) {
                unsigned long long o[16];
                #pragma unroll
                for (int i = 0; i < 16; ++i) o[i] = __shfl_xor(C[i], round, 64);
                #pragma unroll
                for (int i = 0; i < 16; ++i) {
                    unsigned long long b = o[15 - i];
                    C[i] = C[i] < b ? C[i] : b;
                }
                cleanup16(C);
            }
            if (sub == 0) {
                #pragma unroll
                for (int i = 0; i < 16; ++i) qb[(oct + 32) * 32 + i] = C[i];
            }
        } else if (sub == 0) {
            unsigned long long R[16];
            #pragma unroll
            for (int i = 0; i < 16; ++i) R[i] = ~0ULL;
            for (int m = 0; m < M_IND; ++m) {
                float u = uval(Zs[m], mB0, mB1, mB2);
                float d = fmaxf(fmaf(2.0f, u, xqB), 0.0f);
                unsigned long long kk =
                    ((unsigned long long)__float_as_uint(d) << 32) | (unsigned)m;
                if (kk < R[15]) {
                    #pragma unroll
                    for (int j = 0; j < 16; ++j) {
                        unsigned long long t = R[j];
                        bool cc = kk < t;
                        R[j] = cc ? kk : t;
                        kk = cc ? t : kk;
                    }
                }
            }
            #pragma unroll
            for (int i = 0; i < 16; ++i) qb[(oct + 32) * 32 + i] = R[i];
        }
    }
    __syncthreads();

    // ============== PHASE 2: cooperative 4-lane local GP ====================
    // Group g = tid>>2 (point), lane l = tid&3 owns rows r = l+4k.
    {
        int g = tid >> 2, l = tid & 3;
        int n = blockIdx.x * 64 + g;
        int lanebase = (tid & 63) & ~3;   // group base lane within the wave

        int idx[16];
        int iown[4];
        float kvown[4];
        float4 zrown[4];
        #pragma unroll
        for (int a = 0; a < 16; ++a) {
            unsigned long long k = qb[g * 32 + a];
            int ia = (int)(k & 0xFFFFFFFFULL);
            float d = __uint_as_float((unsigned)(k >> 32));
            float kva = __expf(-0.5f * d);
            idx[a] = ia;
            if ((a & 3) == l) {
                iown[a >> 2] = ia;
                kvown[a >> 2] = kva;
                zrown[a >> 2] = Zs[ia];
            }
        }

        // ---- A-build (column-major, owned rows only) ----
        float L0[4], L1[8], L2[12], L3[16];
        float dg[4];
        #pragma unroll
        for (int k = 0; k < 4; ++k) dg[k] = 1.0f + 2.0f * JITTER;
        #pragma unroll
        for (int c = 0; c < 16; ++c) {
            float4 zc = Zs[idx[c]];
            #pragma unroll
            for (int k = 0; k < 4; ++k) {
                if (c < 4 * (k + 1)) {                 // static prune
                    int r = l + 4 * k;
                    float dot = fmaf(zrown[k].x, zc.x,
                                fmaf(zrown[k].y, zc.y, zrown[k].z * zc.z));
                    float val = __expf(fminf(dot - zrown[k].w - zc.w, 0.0f));
                    if (c < r) {
                        if (k == 0) L0[LI0(c)] = val;
                        else if (k == 1) L1[LI1(c)] = val;
                        else if (k == 2) L2[LI2(c)] = val;
                        else L3[c] = val;
                    }
                }
            }
        }

        // ---- Cooperative right-looking Cholesky ----
        float rinvown[4];
        #pragma unroll
        for (int c = 0; c < 16; ++c) {
            const int owner = c & 3, kc = c >> 2;     // static
            float dval = __shfl(dg[kc], lanebase + owner, 64);
            float rinv = __frsqrt_rn(fmaxf(dval, 1e-12f));
            if (l == owner) rinvown[kc] = rinv;
            float cv[4];
            #pragma unroll
            for (int k = 0; k < 4; ++k) {
                cv[k] = 0.f;
                if (c < 4 * (k + 1)) {                // static prune
                    int r = l + 4 * k;
                    if (r > c) {
                        float v;
                        if (k == 0) { v = L0[LI0(c)] * rinv; L0[LI0(c)] = v; }
                        else if (k == 1) { v = L1[LI1(c)] * rinv; L1[LI1(c)] = v; }
                        else if (k == 2) { v = L2[LI2(c)] * rinv; L2[LI2(c)] = v; }
                        else { v = L3[c] * rinv; L3[c] = v; }
                        cv[k] = v;
                    }
                }
            }
            #pragma unroll
            for (int j = c + 1; j < 16; ++j) {        // static j
                float colj = __shfl(cv[j >> 2], lanebase + (j & 3), 64);
                #pragma unroll
                for (int k = 0; k < 4; ++k) {
                    if (j < 4 * (k + 1)) {            // static prune
                        int r = l + 4 * k;
                        if (r > j) {
                            float u = cv[k] * colj;
                            if (k == 0) L0[LI0(j)] -= u;
                            else if (k == 1) L1[LI1(j)] -= u;
                            else if (k == 2) L2[LI2(j)] -= u;
                            else L3[j] -= u;
                        } else if (r == j) {
                            dg[k] = fmaf(-colj, colj, dg[k]);
                        }
                    }
                }
            }
        }

        // ---- Forward solve L y = kv (y stored owned) ----
        float acc[4];
        #pragma unroll
        for (int k = 0; k < 4; ++k) acc[k] = kvown[k];
        float yown[4];
        #pragma unroll
        for (int r = 0; r < 16; ++r) {
            const int owner = r & 3, kr = r >> 2;     // static
            float yr = __shfl(acc[kr] * rinvown[kr], lanebase + owner, 64);
            if (l == owner) yown[kr] = yr;
            #pragma unroll
            for (int k = 0; k < 4; ++k) {
                if (r < 4 * (k + 1)) {                // static prune
                    int rr = l + 4 * k;
                    if (rr > r) {
                        float lv;
                        if (k == 0) lv = L0[LI0(r)];
                        else if (k == 1) lv = L1[LI1(r)];
                        else if (k == 2) lv = L2[LI2(r)];
                        else lv = L3[r];
                        acc[k] = fmaf(-lv, yr, acc[k]);
                    }
                }
            }
        }

        // ---- Backward solve L^T w = y ----
        float wfull[16];
        float wown[4] = {0.f, 0.f, 0.f, 0.f};
        #pragma unroll
        for (int r = 15; r >= 0; --r) {
            const int owner = r & 3, kr = r >> 2;     // static
            float contrib = 0.f;
            #pragma unroll
            for (int k = 0; k < 4; ++k) {
                if (r < 4 * (k + 1)) {                // static prune
                    int j = l + 4 * k;
                    if (j > r) {
                        float lv;
                        if (k == 0) lv = L0[LI0(r)];
                        else if (k == 1) lv = L1[LI1(r)];
                        else if (k == 2) lv = L2[LI2(r)];
                        else lv = L3[r];
                        contrib = fmaf(lv, wown[k], contrib);
                    }
                }
            }
            contrib += __shfl_xor(contrib, 1, 64);
            contrib += __shfl_xor(contrib, 2, 64);
            float wr = __shfl((yown[kr] - contrib) * rinvown[kr],
                              lanebase + owner, 64);
            wfull[r] = wr;
            if (l == owner) wown[kr] = wr;
        }

        // ---- wk, ww, mean (owned + 2-shfl reduce) ----
        float wkp = 0.f, wwp = 0.f, mnp = 0.f;
        #pragma unroll
        for (int k = 0; k < 4; ++k) {
            wkp = fmaf(wown[k], kvown[k], wkp);
            wwp = fmaf(wown[k], wown[k], wwp);
            mnp = fmaf(wown[k], mus[iown[k]], mnp);
        }

        // ---- qs = w^T Su[idx,idx] w, rows split by ownership ----
        float qsp = 0.f;
        #pragma unroll
        for (int k = 0; k < 4; ++k) {
            int r = l + 4 * k;
            int a = iown[k];
            float wr = wown[k];
            float rowacc = 0.f;
            #pragma unroll
            for (int c = 0; c < 15; ++c) {            // static c
                if (c < r) {
                    int b = idx[c];
                    int hi = a > b ? a : b;
                    int lo = a > b ? b : a;
                    rowacc = fmaf(wfull[c], P[((unsigned)hi * (hi + 1) >> 1) + lo], rowacc);
                }
            }
            qsp = fmaf(wr, fmaf(wr, P[((unsigned)a * (a + 1) >> 1) + a], 2.0f * rowacc), qsp);
        }

        wkp += __shfl_xor(wkp, 1, 64); wkp += __shfl_xor(wkp, 2, 64);
        wwp += __shfl_xor(wwp, 1, 64); wwp += __shfl_xor(wwp, 2, 64);
        mnp += __shfl_xor(mnp, 1, 64); mnp += __shfl_xor(mnp, 2, 64);
        qsp += __shfl_xor(qsp, 1, 64); qsp += __shfl_xor(qsp, 2, 64);

        if (l == 0) {
            float cov = 1.0f - (wkp - JITTER * wwp) + qsp;
            float sd = sqrtf(fmaxf(cov, 0.05f));
            out[n] = mnp;
            out[N_PTS + n] = sd;
        }
    }
}

// ---------------------------------------------------------------------------
// MODE 0 exact fallback (no workspace) — R15 kernel, only <0> instantiated.
// ---------------------------------------------------------------------------
template <int MODE>
__global__ __launch_bounds__(256, 2) void vnngp_kernel(const float* __restrict__ X,
                                                       const float* __restrict__ Z,
                                                       const float* __restrict__ mu,
                                                       float* __restrict__ P,
                                                       const float* __restrict__ Lu_raw,
                                                       unsigned int* __restrict__ ctr,
                                                       float* __restrict__ out) {
    __shared__ __align__(16) char smem[37888];
    float4* Zs = (float4*)smem;
    float* mus = (float*)(smem + 16384);
    unsigned long long* qb = (unsigned long long*)(smem + 20480);
    int tid = threadIdx.x;

    for (int r = tid; r < M_IND; r += 256) {
        float zx = Z[r * 3 + 0], zy = Z[r * 3 + 1], zz = Z[r * 3 + 2];
        Zs[r] = make_float4(zx, zy, zz, 0.5f * (zx * zx + zy * zy + zz * zz));
        mus[r] = mu[r];
    }
    __syncthreads();

    {
        int pt = tid >> 2, sub = tid & 3;
        int nA = blockIdx.x * PTS_PER_BLK + pt;
        int nB = nA + 64;
        float xA0 = X[nA * 3 + 0], xA1 = X[nA * 3 + 1], xA2 = X[nA * 3 + 2];
        float xB0 = X[nB * 3 + 0], xB1 = X[nB * 3 + 1], xB2 = X[nB * 3 + 2];
        float xqA = fmaf(xA0, xA0, fmaf(xA1, xA1, xA2 * xA2));
        float xqB = fmaf(xB0, xB0, fmaf(xB1, xB1, xB2 * xB2));
        float nA0 = -xA0, nA1 = -xA1, nA2 = -xA2;
        float nB0 = -xB0, nB1 = -xB1, nB2 = -xB2;
        int mbase = sub << 8;
        int rot = sub << 1;

        float TA[16], TB[16];
        #pragma unroll
        for (int j = 0; j < 16; ++j) { TA[j] = 3.4e38f; TB[j] = 3.4e38f; }
        #pragma unroll 1
        for (int c = 0; c < 16; ++c) {
            int base = mbase + (c << 4);
            #pragma unroll
            for (int j = 0; j < 16; ++j) {
                int m = base + ((j + rot) & 15);
                float4 z = Zs[m];
                TA[j] = fminf(TA[j], uval(z, nA0, nA1, nA2));
                TB[j] = fminf(TB[j], uval(z, nB0, nB1, nB2));
            }
        }
        sort16(TA);
        sort16(TB);
        #pragma unroll
        for (int round = 1; round <= 2; round <<= 1) {
            float oA[16], oB[16];
            #pragma unroll
            for (int i = 0; i < 16; ++i) {
                oA[i] = __shfl_xor(TA[i], round, 64);
                oB[i] = __shfl_xor(TB[i], round, 64);
            }
            #pragma unroll
            for (int i = 0; i < 16; ++i) {
                TA[i] = fminf(TA[i], oA[15 - i]);
                TB[i] = fminf(TB[i], oB[15 - i]);
            }
            cleanup16(TA);
            cleanup16(TB);
        }
        float TstarA = TA[15], TstarB = TB[15];

        unsigned short* mycA = ((unsigned short*)qb) + pt * (QSTRIDE * 4) + sub * 16;
        unsigned short* mycB = ((unsigned short*)qb) + (pt + 64) * (QSTRIDE * 4) + sub * 16;
        int cntA = 0, cntB = 0;
        #pragma unroll 1
        for (int c = 0; c < 16; ++c) {
            int base = mbase + (c << 4);
            #pragma unroll
            for (int j = 0; j < 16; ++j) {
                int m = base + ((j + rot) & 15);
                float4 z = Zs[m];
                float uA = uval(z, nA0, nA1, nA2);
                float uB = uval(z, nB0, nB1, nB2);
                if (uA <= TstarA) { if (cntA < 16) mycA[cntA] = (unsigned short)m; ++cntA; }
                if (uB <= TstarB) { if (cntB < 16) mycB[cntB] = (unsigned short)m; ++cntB; }
            }
        }

        int ovfA = cntA > 16 ? 1 : 0;
        ovfA |= __shfl_xor(ovfA, 1, 64);
        ovfA |= __shfl_xor(ovfA, 2, 64);
        int ovfB = cntB > 16 ? 1 : 0;
        ovfB |= __shfl_xor(ovfB, 1, 64);
        ovfB |= __shfl_xor(ovfB, 2, 64);

        if (!ovfA) {
            const unsigned long long* m64 = (const unsigned long long*)mycA;
            unsigned long long raw[4] = {m64[0], m64[1], m64[2], m64[3]};
            unsigned long long C[16];
            #pragma unroll
            for (int i = 0; i < 16; ++i) {
                int m = (int)((raw[i >> 2] >> ((i & 3) * 16)) & 0x3FF);
                float u = uval(Zs[m], nA0, nA1, nA2);
                float d = fmaxf(fmaf(2.0f, u, xqA), 0.0f);
                unsigned long long key =
                    ((unsigned long long)__float_as_uint(d) << 32) | (unsigned)m;
                C[i] = (i < cntA) ? key : ~0ULL;
            }
            sort16(C);
            #pragma unroll
            for (int round = 1; round <= 2; round <<= 1) {
                unsigned long long o[16];
                #pragma unroll
                for (int i = 0; i < 16; ++i) o[i] = __shfl_xor(C[i], round, 64);
                #pragma unroll
                for (int i = 0; i < 16; ++i) {
                    unsigned long long b = o[15 - i];
                    C[i] = C[i] < b ? C[i] : b;
                }
                cleanup16(C);
            }
            if (sub == 0) {
                #pragma unroll
                for (int i = 0; i < 16; ++i) qb[pt * QSTRIDE + i] = C[i];
            }
        } else if (sub == 0) {
            unsigned long long R[16];
            #pragma unroll
            for (int i = 0; i < 16; ++i) R[i] = ~0ULL;
            for (int m = 0; m < M_IND; ++m) {
                float u = uval(Zs[m], nA0, nA1, nA2);
                float d = fmaxf(fmaf(2.0f, u, xqA), 0.0f);
                unsigned long long kk =
                    ((unsigned long long)__float_as_uint(d) << 32) | (unsigned)m;
                if (kk < R[15]) {
                    #pragma unroll
                    for (int j = 0; j < 16; ++j) {
                        unsigned long long t = R[j];
                        bool cc = kk < t;
                        R[j] = cc ? kk : t;
                        kk = cc ? t : kk;
                    }
                }
            }
            #pragma unroll
            for (int i = 0; i < 16; ++i) qb[pt * QSTRIDE + i] = R[i];
        }

        if (!ovfB) {
            const unsigned long long* m64 = (const unsigned long long*)mycB;
            unsigned long long raw[4] = {m64[0], m64[1], m64[2], m64[3]};
            unsigned long long C[16];
            #pragma unroll
            for (int i = 0; i < 16; ++i) {
                int m = (int)((raw[i >> 2] >> ((i & 3) * 16)) & 0x3FF);
                float u = uval(Zs[m], nB0, nB1, nB2);
                float d = fmaxf(fmaf(2.0f, u, xqB), 0.0f);
                unsigned long long key =
                    ((unsigned long long)__float_as_uint(d) << 32) | (unsigned)m;
                C[i] = (i < cntB) ? key : ~0ULL;
            }
            sort16(C);
            #pragma unroll
            for (int round = 1; round <= 2; round <<= 1) {
                unsigned long long o[16];
                #pragma unroll
                for (int i = 0; i < 16; ++i) o[i] = __shfl_xor(C[i], round, 64);
                #pragma unroll
                for (int i = 0; i < 16; ++i) {
                    unsigned long long b = o[15 - i];
                    C[i] = C[i] < b ? C[i] : b;
                }
                cleanup16(C);
            }
            if (sub == 0) {
                #pragma unroll
                for (int i = 0; i < 16; ++i) qb[(pt + 64) * QSTRIDE + i] = C[i];
            }
        } else if (sub == 0) {
            unsigned long long R[16];
            #pragma unroll
            for (int i = 0; i < 16; ++i) R[i] = ~0ULL;
            for (int m = 0; m < M_IND; ++m) {
                float u = uval(Zs[m], nB0, nB1, nB2);
                float d = fmaxf(fmaf(2.0f, u, xqB), 0.0f);
                unsigned long long kk =
                    ((unsigned long long)__float_as_uint(d) << 32) | (unsigned)m;
                if (kk < R[15]) {
                    #pragma unroll
                    for (int j = 0; j < 16; ++j) {
                        unsigned long long t = R[j];
                        bool cc = kk < t;
                        R[j] = cc ? kk : t;
                        kk = cc ? t : kk;
                    }
                }
            }
            #pragma unroll
            for (int i = 0; i < 16; ++i) qb[(pt + 64) * QSTRIDE + i] = R[i];
        }
    }
    __syncthreads();

    int role = tid >> 7;
    int pt2 = tid & 127;
    int n = blockIdx.x * PTS_PER_BLK + pt2;
    int idx[KNN];
    float kv[KNN];
    float nx[KNN], ny[KNN], nz[KNN], nq[KNN];
    #pragma unroll
    for (int a = 0; a < KNN; ++a) {
        unsigned long long k = qb[pt2 * QSTRIDE + a];
        idx[a] = (int)(k & 0xFFFFFFFFULL);
        float d = __uint_as_float((unsigned)(k >> 32));
        kv[a] = __expf(-0.5f * d);
        float4 z = Zs[idx[a]];
        nx[a] = z.x; ny[a] = z.y; nz[a] = z.z; nq[a] = z.w;
    }
    __syncthreads();

    float A[KNN * (KNN + 1) / 2];
    #pragma unroll
    for (int r = 0; r < KNN; ++r) {
        A[r * (r + 1) / 2 + r] = 1.0f + 2.0f * JITTER;
        #pragma unroll
        for (int c = 0; c < r; ++c) {
            float dot = fmaf(nx[r], nx[c], fmaf(ny[r], ny[c], nz[r] * nz[c]));
            A[r * (r + 1) / 2 + c] = __expf(fminf(dot - nq[r] - nq[c], 0.0f));
        }
    }

    #pragma unroll
    for (int c = 0; c < KNN; ++c) {
        float diag = A[c * (c + 1) / 2 + c];
        #pragma unroll
        for (int k = 0; k < c; ++k) {
            float lv = A[c * (c + 1) / 2 + k];
            diag = fmaf(-lv, lv, diag);
        }
        float rinv = __frsqrt_rn(fmaxf(diag, 1e-12f));
        A[c * (c + 1) / 2 + c] = rinv;
        #pragma unroll
        for (int r = c + 1; r < KNN; ++r) {
            float v = A[r * (r + 1) / 2 + c];
            #pragma unroll
            for (int k = 0; k < c; ++k)
                v = fmaf(-A[r * (r + 1) / 2 + k], A[c * (c + 1) / 2 + k], v);
            A[r * (r + 1) / 2 + c] = v * rinv;
        }
    }

    float w[KNN];
    #pragma unroll
    for (int r = 0; r < KNN; ++r) {
        float v = kv[r];
        #pragma unroll
        for (int c = 0; c < r; ++c) v = fmaf(-A[r * (r + 1) / 2 + c], w[c], v);
        w[r] = v * A[r * (r + 1) / 2 + r];
    }
    #pragma unroll
    for (int r = KNN - 1; r >= 0; --r) {
        float v = w[r];
        #pragma unroll
        for (int c = r + 1; c < KNN; ++c) v = fmaf(-A[c * (c + 1) / 2 + r], w[c], v);
        w[r] = v * A[r * (r + 1) / 2 + r];
    }

    float wk = 0.f, ww = 0.f, mean = 0.f;
    #pragma unroll
    for (int a = 0; a < KNN; ++a) {
        wk = fmaf(w[a], kv[a], wk);
        ww = fmaf(w[a], w[a], ww);
        mean = fmaf(w[a], mus[idx[a]], mean);
    }

    float qs_p = 0.f;
    if (role == 0) {
        int si[KNN]; float sw[KNN];
        #pragma unroll
        for (int a = 0; a < KNN; ++a) { si[a] = idx[a]; sw[a] = w[a]; }
        #pragma unroll
        for (int a = 1; a < KNN; ++a) {
            int iv = si[a]; float wv = sw[a];
            int b = a - 1;
            while (b >= 0 && si[b] > iv) { si[b + 1] = si[b]; sw[b + 1] = sw[b]; --b; }
            si[b + 1] = iv; sw[b + 1] = wv;
        }
        int s = 0;
        int kend = si[KNN - 1];
        for (int k = 0; k <= kend; ++k) {
            float v = 0.f;
            if (s < KNN && si[s] == k) {
                v = sw[s] * __expf(Lu_raw[(unsigned)k * M_IND + k]);
                ++s;
            }
            for (int a = s; a < KNN; ++a)
                v = fmaf(sw[a], Lu_raw[(unsigned)si[a] * M_IND + k], v);
            qs_p = fmaf(v, v, qs_p);
        }
    }

    float* xch = (float*)qb;
    if (role == 1) xch[pt2] = qs_p;
    __syncthreads();
    if (role == 0) {
        float qs = qs_p + xch[pt2];
        float cov = 1.0f - (wk - JITTER * ww) + qs;
        float sd = sqrtf(fmaxf(cov, 0.05f));
        out[n] = mean;
        out[N_PTS + n] = sd;
    }
}

// ---------------------------------------------------------------------------
extern "C" void kernel_launch(void* const* d_in, const int* in_sizes, int n_in,
                              void* d_out, int out_size, void* d_ws, size_t ws_size,
                              hipStream_t stream) {
    const float* X      = (const float*)d_in[0];
    const float* Z      = (const float*)d_in[1];
    const float* Lu_raw = (const float*)d_in[2];
    const float* mu     = (const float*)d_in[3];
    float* out = (float*)d_out;

    if (ws_size >= PACKED_BYTES) {
        // Split: su (P in d_ws) then fused selection+phase2. Stream order is
        // the sync — no counter, no memset, no co-residency requirement.
        float* P = (float*)d_ws;
        su_kernel<<<SU_BLOCKS, 256, 0, stream>>>(Lu_raw, P);
        selp2_kernel<<<N_PTS / 64, 256, 0, stream>>>(X, Z, mu, P, out);
    } else {
        vnngp_kernel<0><<<GRID_BLKS, 256, 0, stream>>>(X, Z, mu, nullptr, Lu_raw, nullptr, out);
    }
}

// Round 7
// 176.023 us; speedup vs baseline: 1.0653x; 1.0653x over previous
//
#include <hip/hip_runtime.h>
#include <math.h>

#define N_PTS 65536
#define M_IND 1024
#define KNN 16
#define JITTER 1e-4f

// Packed lower-triangular Su: P[i*(i+1)/2 + j], j <= i.
#define PACKED_FLOATS (M_IND * (M_IND + 1) / 2)               // 524800
#define PACKED_BYTES  ((size_t)PACKED_FLOATS * sizeof(float)) // 2,099,200 B

#define TSU 32
#define SU_BLOCKS 528          // 32*33/2 triangular tiles
#define PTS_PER_BLK 128        // 512 blocks, 2/CU resident
#define QSTRIDE 17             // u64 per point row (136 B)
#define GRID_BLKS (N_PTS / PTS_PER_BLK)   // 512

// R17 ledger:
//  - LAW (R11/R12/R16 triple-confirmed): this code needs the full 256-reg
//    unified budget -> (256,2) only. Any tighter cap spills (R16: 47 MB
//    WRITE_SIZE at (256,4) despite VGPR_Count=64).
//  - Selection is LDS-THROUGHPUT-bound: 1.34e8 x 16B Zs reads / 256 CU /
//    85 B/cyc ~= 41 us floor, occupancy-independent (R14: 4 blk/CU sel not
//    faster). Next lever if needed: more dists per LDS read.
//  - Phase 2 is the serial Cholesky chain (R15: qs-split no-op). R16's
//    cooperative 4-lane phase 2 PASSED correctness -> reused here verbatim
//    inside the proven R13 fused frame, 2 batches x 64 pts, all 256 threads.
//  - Spill tripwire: WRITE_SIZE must stay ~3 MB.

// ---------------------------------------------------------------------------
// One 32x32 Su tile (packed tril(Lu Lu^T)). As/Bs are LDS scratch.
// ---------------------------------------------------------------------------
__device__ __forceinline__ void su_tile(const float* __restrict__ Lu_raw,
                                        float* __restrict__ P,
                                        int bid, int tid,
                                        float (*As)[36], float (*Bs)[36]) {
    int rt = (int)((sqrtf(8.0f * (float)bid + 1.0f) - 1.0f) * 0.5f);
    while ((rt + 1) * (rt + 2) / 2 <= bid) ++rt;
    while (rt * (rt + 1) / 2 > bid) --rt;
    int ct = bid - rt * (rt + 1) / 2;   // ct <= rt
    int i0 = rt * TSU, j0 = ct * TSU;

    int tx = tid & 15, ty = tid >> 4;
    int sr = tid >> 3, sc = (tid & 7) << 2;
    float a00 = 0.f, a01 = 0.f, a10 = 0.f, a11 = 0.f;

    int nch = ct + 1;                      // k-chunks of 32 (k <= j0+31)
    int gi = i0 + sr, gj = j0 + sr;
    float4 pa = *(const float4*)(Lu_raw + (unsigned)gi * M_IND + sc);
    float4 pb = *(const float4*)(Lu_raw + (unsigned)gj * M_IND + sc);

    for (int c = 0; c < nch; ++c) {
        int gk = (c << 5) + sc;
        float aa[4] = {pa.x, pa.y, pa.z, pa.w};
        float bb[4] = {pb.x, pb.y, pb.z, pb.w};
        #pragma unroll
        for (int q = 0; q < 4; ++q) {
            int k = gk + q;
            aa[q] = (k < gi) ? aa[q] : ((k == gi) ? __expf(aa[q]) : 0.0f);
            bb[q] = (k < gj) ? bb[q] : ((k == gj) ? __expf(bb[q]) : 0.0f);
        }
        *(float4*)&As[sr][sc] = make_float4(aa[0], aa[1], aa[2], aa[3]);
        *(float4*)&Bs[sr][sc] = make_float4(bb[0], bb[1], bb[2], bb[3]);
        __syncthreads();
        if (c + 1 < nch) {
            int kn = ((c + 1) << 5) + sc;
            pa = *(const float4*)(Lu_raw + (unsigned)gi * M_IND + kn);
            pb = *(const float4*)(Lu_raw + (unsigned)gj * M_IND + kn);
        }
        #pragma unroll
        for (int kk = 0; kk < 32; kk += 4) {
            float4 av0 = *(const float4*)&As[ty][kk];
            float4 av1 = *(const float4*)&As[ty + 16][kk];
            float4 bv0 = *(const float4*)&Bs[tx][kk];
            float4 bv1 = *(const float4*)&Bs[tx + 16][kk];
            a00 = fmaf(av0.x, bv0.x, fmaf(av0.y, bv0.y, fmaf(av0.z, bv0.z, fmaf(av0.w, bv0.w, a00))));
            a01 = fmaf(av0.x, bv1.x, fmaf(av0.y, bv1.y, fmaf(av0.z, bv1.z, fmaf(av0.w, bv1.w, a01))));
            a10 = fmaf(av1.x, bv0.x, fmaf(av1.y, bv0.y, fmaf(av1.z, bv0.z, fmaf(av1.w, bv0.w, a10))));
            a11 = fmaf(av1.x, bv1.x, fmaf(av1.y, bv1.y, fmaf(av1.z, bv1.z, fmaf(av1.w, bv1.w, a11))));
        }
        __syncthreads();
    }

    int ia = i0 + ty, ib = i0 + ty + 16;
    int ja = j0 + tx, jb = j0 + tx + 16;
    if (ja <= ia) P[((unsigned)ia * (ia + 1) >> 1) + ja] = a00;
    if (jb <= ia) P[((unsigned)ia * (ia + 1) >> 1) + jb] = a01;
    if (ja <= ib) P[((unsigned)ib * (ib + 1) >> 1) + ja] = a10;
    if (jb <= ib) P[((unsigned)ib * (ib + 1) >> 1) + jb] = a11;
}

// Standalone su kernel (non-fused fallback path only).
__global__ __launch_bounds__(256) void su_kernel(const float* __restrict__ Lu_raw,
                                                 float* __restrict__ P) {
    __shared__ float As[TSU][36];
    __shared__ float Bs[TSU][36];
    su_tile(Lu_raw, P, blockIdx.x, threadIdx.x, As, Bs);
}

// ---------------------------------------------------------------------------
// Sorting-network helpers.
// ---------------------------------------------------------------------------
__device__ __forceinline__ void ce(unsigned long long& x, unsigned long long& y) {
    unsigned long long a = x, b = y;
    bool c = a < b;
    x = c ? a : b;
    y = c ? b : a;
}
__device__ __forceinline__ void ce(float& x, float& y) {
    float a = fminf(x, y), b = fmaxf(x, y);
    x = a; y = b;
}

template <typename KT>
__device__ __forceinline__ void sort16(KT* a) {
    #pragma unroll
    for (int p = 1; p < 16; p <<= 1)
        #pragma unroll
        for (int k = p; k >= 1; k >>= 1)
            #pragma unroll
            for (int j = k & (p - 1); j + k < 16; j += 2 * k)
                #pragma unroll
                for (int i = 0; i < k; ++i)
                    if (i + j + k < 16)
                        if (((i + j) / (2 * p)) == ((i + j + k) / (2 * p)))
                            ce(a[i + j], a[i + j + k]);
}

template <typename KT>
__device__ __forceinline__ void cleanup16(KT* a) {
    #pragma unroll
    for (int d = 8; d >= 1; d >>= 1)
        #pragma unroll
        for (int i = 0; i < 16; ++i)
            if ((i & d) == 0) ce(a[i], a[i | d]);
}

// u-space distance surrogate: u = 0.5*|z|^2 - x.z  (Zs.w holds 0.5*|z|^2).
// d = max(2u + xq, 0) is monotone in u.
__device__ __forceinline__ float uval(float4 z, float xn0, float xn1, float xn2) {
    return fmaf(xn0, z.x, fmaf(xn1, z.y, fmaf(xn2, z.z, z.w)));
}

// Static-index accessors for the row-cyclic L storage (lane l owns rows
// l, l+4, l+8, l+12). Clamps keep dead unrolled branches in-bounds; always
// used under the static guard (c) < 4*(k+1). (Validated in R16.)
#define LI0(c) ((c) & 3)
#define LI1(c) ((c) & 7)
#define LI2(c) ((c) < 12 ? (c) : 0)

// ---------------------------------------------------------------------------
// MODE 2: fused (su tiles in-kernel + device-flag sync). MODE 1: two-kernel.
// MODE 0: no-workspace exact fallback (serial phase 2).
// 512 blocks x 256 thr, 128 pts/blk, selection: 4 subs x 2 pts/thread;
// phase 2 (MODE!=0): cooperative 4-lane, 2 batches of 64 points.
// ---------------------------------------------------------------------------
template <int MODE>
__global__ __launch_bounds__(256, 2) void vnngp_kernel(const float* __restrict__ X,
                                                       const float* __restrict__ Z,
                                                       const float* __restrict__ mu,
                                                       float* __restrict__ P,
                                                       const float* __restrict__ Lu_raw,
                                                       unsigned int* __restrict__ ctr,
                                                       float* __restrict__ out) {
    __shared__ __align__(16) char smem[37888];
    float4* Zs = (float4*)smem;                                  // 16 KB
    float* mus = (float*)(smem + 16384);                         // 4 KB
    unsigned long long* qb = (unsigned long long*)(smem + 20480); // 17 KB
    int tid = threadIdx.x;

    for (int r = tid; r < M_IND; r += 256) {
        float zx = Z[r * 3 + 0], zy = Z[r * 3 + 1], zz = Z[r * 3 + 2];
        Zs[r] = make_float4(zx, zy, zz, 0.5f * (zx * zx + zy * zy + zz * zz));
        mus[r] = mu[r];
    }

    if (MODE == 2) {
        // In-kernel Su tiles (As/Bs alias the qb region: 9216 <= 17408 B).
        // Tile permutation: the 16 grid-stride "extra" tiles are the CHEAP
        // ct=0 single-chunk tiles (ids r(r+1)/2, r=16..31); the main
        // assignment skips them, so no block stacks a second expensive tile.
        float (*As)[36] = (float (*)[36])(smem + 20480);
        float (*Bs)[36] = (float (*)[36])(smem + 20480 + 4608);
        int t = blockIdx.x;
        #pragma unroll
        for (int r = 16; r < 32; ++r) {
            int s = (r * (r + 1)) >> 1;
            if (t >= s) ++t;
        }
        su_tile(Lu_raw, P, t, tid, As, Bs);       // contains __syncthreads
        if (blockIdx.x < 16) {
            int r = 16 + blockIdx.x;
            su_tile(Lu_raw, P, (r * (r + 1)) >> 1, tid, As, Bs);
        }
        __syncthreads();                           // P stores drained (vmcnt)
        if (tid == 0) {
            __threadfence();                       // device-scope release
            atomicAdd(ctr, 1u);
        }
    } else {
        __syncthreads();
    }

    {
        int pt = tid >> 2, sub = tid & 3;     // pt 0..63, quad handles pt & pt+64
        int nA = blockIdx.x * PTS_PER_BLK + pt;
        int nB = nA + 64;
        float xA0 = X[nA * 3 + 0], xA1 = X[nA * 3 + 1], xA2 = X[nA * 3 + 2];
        float xB0 = X[nB * 3 + 0], xB1 = X[nB * 3 + 1], xB2 = X[nB * 3 + 2];
        float xqA = fmaf(xA0, xA0, fmaf(xA1, xA1, xA2 * xA2));
        float xqB = fmaf(xB0, xB0, fmaf(xB1, xB1, xB2 * xB2));
        float nA0 = -xA0, nA1 = -xA1, nA2 = -xA2;
        float nB0 = -xB0, nB1 = -xB1, nB2 = -xB2;
        int mbase = sub << 8;
        int rot = sub << 1;   // subs land on disjoint bank quads

        // ---- Pass 1: 16 interleaved class minima per point (u-space) ----
        float TA[16], TB[16];
        #pragma unroll
        for (int j = 0; j < 16; ++j) { TA[j] = 3.4e38f; TB[j] = 3.4e38f; }
        #pragma unroll 1
        for (int c = 0; c < 16; ++c) {
            int base = mbase + (c << 4);
            #pragma unroll
            for (int j = 0; j < 16; ++j) {
                int m = base + ((j + rot) & 15);
                float4 z = Zs[m];
                TA[j] = fminf(TA[j], uval(z, nA0, nA1, nA2));
                TB[j] = fminf(TB[j], uval(z, nB0, nB1, nB2));
            }
        }
        sort16(TA);
        sort16(TB);
        #pragma unroll
        for (int round = 1; round <= 2; round <<= 1) {
            float oA[16], oB[16];
            #pragma unroll
            for (int i = 0; i < 16; ++i) {
                oA[i] = __shfl_xor(TA[i], round, 64);
                oB[i] = __shfl_xor(TB[i], round, 64);
            }
            #pragma unroll
            for (int i = 0; i < 16; ++i) {
                TA[i] = fminf(TA[i], oA[15 - i]);
                TB[i] = fminf(TB[i], oB[15 - i]);
            }
            cleanup16(TA);
            cleanup16(TB);
        }
        float TstarA = TA[15], TstarB = TB[15];   // u-space thresholds

        // ---- Pass 2: collect indices with u <= Tstar (u16, cap 16/sub) ----
        unsigned short* mycA = ((unsigned short*)qb) + pt * (QSTRIDE * 4) + sub * 16;
        unsigned short* mycB = ((unsigned short*)qb) + (pt + 64) * (QSTRIDE * 4) + sub * 16;
        int cntA = 0, cntB = 0;
        #pragma unroll 1
        for (int c = 0; c < 16; ++c) {
            int base = mbase + (c << 4);
            #pragma unroll
            for (int j = 0; j < 16; ++j) {
                int m = base + ((j + rot) & 15);
                float4 z = Zs[m];
                float uA = uval(z, nA0, nA1, nA2);
                float uB = uval(z, nB0, nB1, nB2);
                if (uA <= TstarA) { if (cntA < 16) mycA[cntA] = (unsigned short)m; ++cntA; }
                if (uB <= TstarB) { if (cntB < 16) mycB[cntB] = (unsigned short)m; ++cntB; }
            }
        }

        int ovfA = cntA > 16 ? 1 : 0;
        ovfA |= __shfl_xor(ovfA, 1, 64);
        ovfA |= __shfl_xor(ovfA, 2, 64);
        int ovfB = cntB > 16 ? 1 : 0;
        ovfB |= __shfl_xor(ovfB, 1, 64);
        ovfB |= __shfl_xor(ovfB, 2, 64);

        // ---- finalize point A ----
        if (!ovfA) {
            const unsigned long long* m64 = (const unsigned long long*)mycA;
            unsigned long long raw[4] = {m64[0], m64[1], m64[2], m64[3]};
            unsigned long long C[16];
            #pragma unroll
            for (int i = 0; i < 16; ++i) {
                int m = (int)((raw[i >> 2] >> ((i & 3) * 16)) & 0x3FF);
                float u = uval(Zs[m], nA0, nA1, nA2);
                float d = fmaxf(fmaf(2.0f, u, xqA), 0.0f);
                unsigned long long key =
                    ((unsigned long long)__float_as_uint(d) << 32) | (unsigned)m;
                C[i] = (i < cntA) ? key : ~0ULL;
            }
            sort16(C);
            #pragma unroll
            for (int round = 1; round <= 2; round <<= 1) {
                unsigned long long o[16];
                #pragma unroll
                for (int i = 0; i < 16; ++i) o[i] = __shfl_xor(C[i], round, 64);
                #pragma unroll
                for (int i = 0; i < 16; ++i) {
                    unsigned long long b = o[15 - i];
                    C[i] = C[i] < b ? C[i] : b;
                }
                cleanup16(C);
            }
            if (sub == 0) {
                #pragma unroll
                for (int i = 0; i < 16; ++i) qb[pt * QSTRIDE + i] = C[i];
            }
        } else if (sub == 0) {
            unsigned long long R[16];
            #pragma unroll
            for (int i = 0; i < 16; ++i) R[i] = ~0ULL;
            for (int m = 0; m < M_IND; ++m) {
                float u = uval(Zs[m], nA0, nA1, nA2);
                float d = fmaxf(fmaf(2.0f, u, xqA), 0.0f);
                unsigned long long kk =
                    ((unsigned long long)__float_as_uint(d) << 32) | (unsigned)m;
                if (kk < R[15]) {
                    #pragma unroll
                    for (int j = 0; j < 16; ++j) {
                        unsigned long long t = R[j];
                        bool cc = kk < t;
                        R[j] = cc ? kk : t;
                        kk = cc ? t : kk;
                    }
                }
            }
            #pragma unroll
            for (int i = 0; i < 16; ++i) qb[pt * QSTRIDE + i] = R[i];
        }

        // ---- finalize point B ----
        if (!ovfB) {
            const unsigned long long* m64 = (const unsigned long long*)mycB;
            unsigned long long raw[4] = {m64[0], m64[1], m64[2], m64[3]};
            unsigned long long C[16];
            #pragma unroll
            for (int i = 0; i < 16; ++i) {
                int m = (int)((raw[i >> 2] >> ((i & 3) * 16)) & 0x3FF);
                float u = uval(Zs[m], nB0, nB1, nB2);
                float d = fmaxf(fmaf(2.0f, u, xqB), 0.0f);
                unsigned long long key =
                    ((unsigned long long)__float_as_uint(d) << 32) | (unsigned)m;
                C[i] = (i < cntB) ? key : ~0ULL;
            }
            sort16(C);
            #pragma unroll
            for (int round = 1; round <= 2; round <<= 1) {
                unsigned long long o[16];
                #pragma unroll
                for (int i = 0; i < 16; ++i) o[i] = __shfl_xor(C[i], round, 64);
                #pragma unroll
                for (int i = 0; i < 16; ++i) {
                    unsigned long long b = o[15 - i];
                    C[i] = C[i] < b ? C[i] : b;
                }
                cleanup16(C);
            }
            if (sub == 0) {
                #pragma unroll
                for (int i = 0; i < 16; ++i) qb[(pt + 64) * QSTRIDE + i] = C[i];
            }
        } else if (sub == 0) {
            unsigned long long R[16];
            #pragma unroll
            for (int i = 0; i < 16; ++i) R[i] = ~0ULL;
            for (int m = 0; m < M_IND; ++m) {
                float u = uval(Zs[m], nB0, nB1, nB2);
                float d = fmaxf(fmaf(2.0f, u, xqB), 0.0f);
                unsigned long long kk =
                    ((unsigned long long)__float_as_uint(d) << 32) | (unsigned)m;
                if (kk < R[15]) {
                    #pragma unroll
                    for (int j = 0; j < 16; ++j) {
                        unsigned long long t = R[j];
                        bool cc = kk < t;
                        R[j] = cc ? kk : t;
                        kk = cc ? t : kk;
                    }
                }
            }
            #pragma unroll
            for (int i = 0; i < 16; ++i) qb[(pt + 64) * QSTRIDE + i] = R[i];
        }
    }
    __syncthreads();

    if (MODE == 2) {
        // Wait for all blocks' Su tiles (selection above overlapped them).
        if (tid == 0) {
            while (__hip_atomic_load(ctr, __ATOMIC_ACQUIRE, __HIP_MEMORY_SCOPE_AGENT)
                   < (unsigned)GRID_BLKS)
                __builtin_amdgcn_s_sleep(8);
        }
        __syncthreads();
    }

    if (MODE == 0) {
        // ---- Serial phase 2 (exact fallback; P unavailable) ----
        if (tid >= PTS_PER_BLK) return;
        int n = blockIdx.x * PTS_PER_BLK + tid;
        int idx[KNN];
        float kv[KNN];
        float nx[KNN], ny[KNN], nz[KNN], nq[KNN];
        #pragma unroll
        for (int a = 0; a < KNN; ++a) {
            unsigned long long k = qb[tid * QSTRIDE + a];
            idx[a] = (int)(k & 0xFFFFFFFFULL);
            float d = __uint_as_float((unsigned)(k >> 32));
            kv[a] = __expf(-0.5f * d);
            float4 z = Zs[idx[a]];
            nx[a] = z.x; ny[a] = z.y; nz[a] = z.z; nq[a] = z.w;
        }

        float A[KNN * (KNN + 1) / 2];
        #pragma unroll
        for (int r = 0; r < KNN; ++r) {
            A[r * (r + 1) / 2 + r] = 1.0f + 2.0f * JITTER;
            #pragma unroll
            for (int c = 0; c < r; ++c) {
                float dot = fmaf(nx[r], nx[c], fmaf(ny[r], ny[c], nz[r] * nz[c]));
                A[r * (r + 1) / 2 + c] = __expf(fminf(dot - nq[r] - nq[c], 0.0f));
            }
        }

        #pragma unroll
        for (int c = 0; c < KNN; ++c) {
            float diag = A[c * (c + 1) / 2 + c];
            #pragma unroll
            for (int k = 0; k < c; ++k) {
                float lv = A[c * (c + 1) / 2 + k];
                diag = fmaf(-lv, lv, diag);
            }
            float rinv = __frsqrt_rn(fmaxf(diag, 1e-12f));
            A[c * (c + 1) / 2 + c] = rinv;
            #pragma unroll
            for (int r = c + 1; r < KNN; ++r) {
                float v = A[r * (r + 1) / 2 + c];
                #pragma unroll
                for (int k = 0; k < c; ++k)
                    v = fmaf(-A[r * (r + 1) / 2 + k], A[c * (c + 1) / 2 + k], v);
                A[r * (r + 1) / 2 + c] = v * rinv;
            }
        }

        float w[KNN];
        #pragma unroll
        for (int r = 0; r < KNN; ++r) {
            float v = kv[r];
            #pragma unroll
            for (int c = 0; c < r; ++c) v = fmaf(-A[r * (r + 1) / 2 + c], w[c], v);
            w[r] = v * A[r * (r + 1) / 2 + r];
        }
        #pragma unroll
        for (int r = KNN - 1; r >= 0; --r) {
            float v = w[r];
            #pragma unroll
            for (int c = r + 1; c < KNN; ++c) v = fmaf(-A[c * (c + 1) / 2 + r], w[c], v);
            w[r] = v * A[r * (r + 1) / 2 + r];
        }

        float wk = 0.f, ww = 0.f, mean = 0.f;
        #pragma unroll
        for (int a = 0; a < KNN; ++a) {
            wk = fmaf(w[a], kv[a], wk);
            ww = fmaf(w[a], w[a], ww);
            mean = fmaf(w[a], mus[idx[a]], mean);
        }

        // On-demand qs from Lu_raw.
        float qs = 0.f;
        {
            int si[KNN]; float sw[KNN];
            #pragma unroll
            for (int a = 0; a < KNN; ++a) { si[a] = idx[a]; sw[a] = w[a]; }
            #pragma unroll
            for (int a = 1; a < KNN; ++a) {
                int iv = si[a]; float wv = sw[a];
                int b = a - 1;
                while (b >= 0 && si[b] > iv) { si[b + 1] = si[b]; sw[b + 1] = sw[b]; --b; }
                si[b + 1] = iv; sw[b + 1] = wv;
            }
            int s = 0;
            int kend = si[KNN - 1];
            for (int k = 0; k <= kend; ++k) {
                float v = 0.f;
                if (s < KNN && si[s] == k) {
                    v = sw[s] * __expf(Lu_raw[(unsigned)k * M_IND + k]);
                    ++s;
                }
                for (int a = s; a < KNN; ++a)
                    v = fmaf(sw[a], Lu_raw[(unsigned)si[a] * M_IND + k], v);
                qs = fmaf(v, v, qs);
            }
        }

        float cov = 1.0f - (wk - JITTER * ww) + qs;
        float sd = sqrtf(fmaxf(cov, 0.05f));
        out[n] = mean;
        out[N_PTS + n] = sd;
        return;
    }

    // ---- Phase 2 (MODE != 0): cooperative 4-lane local GP (validated R16),
    // 2 batches of 64 points; all 256 threads active.
    {
        int l = tid & 3;
        int lanebase = (tid & 63) & ~3;   // group base lane within the wave

        #pragma unroll 1
        for (int b = 0; b < 2; ++b) {
            int g = (tid >> 2) + (b << 6);        // point within block
            int n = blockIdx.x * PTS_PER_BLK + g;

            int idx[16];
            int iown[4];
            float kvown[4];
            float4 zrown[4];
            #pragma unroll
            for (int a = 0; a < 16; ++a) {
                unsigned long long k = qb[g * QSTRIDE + a];
                int ia = (int)(k & 0xFFFFFFFFULL);
                float d = __uint_as_float((unsigned)(k >> 32));
                float kva = __expf(-0.5f * d);
                idx[a] = ia;
                if ((a & 3) == l) {
                    iown[a >> 2] = ia;
                    kvown[a >> 2] = kva;
                    zrown[a >> 2] = Zs[ia];
                }
            }

            // ---- A-build (owned rows only) ----
            float L0[4], L1[8], L2[12], L3[16];
            float dg[4];
            #pragma unroll
            for (int k = 0; k < 4; ++k) dg[k] = 1.0f + 2.0f * JITTER;
            #pragma unroll
            for (int c = 0; c < 16; ++c) {
                float4 zc = Zs[idx[c]];
                #pragma unroll
                for (int k = 0; k < 4; ++k) {
                    if (c < 4 * (k + 1)) {                 // static prune
                        int r = l + 4 * k;
                        float dot = fmaf(zrown[k].x, zc.x,
                                    fmaf(zrown[k].y, zc.y, zrown[k].z * zc.z));
                        float val = __expf(fminf(dot - zrown[k].w - zc.w, 0.0f));
                        if (c < r) {
                            if (k == 0) L0[LI0(c)] = val;
                            else if (k == 1) L1[LI1(c)] = val;
                            else if (k == 2) L2[LI2(c)] = val;
                            else L3[c] = val;
                        }
                    }
                }
            }

            // ---- Cooperative right-looking Cholesky ----
            float rinvown[4];
            #pragma unroll
            for (int c = 0; c < 16; ++c) {
                const int owner = c & 3, kc = c >> 2;     // static
                float dval = __shfl(dg[kc], lanebase + owner, 64);
                float rinv = __frsqrt_rn(fmaxf(dval, 1e-12f));
                if (l == owner) rinvown[kc] = rinv;
                float cv[4];
                #pragma unroll
                for (int k = 0; k < 4; ++k) {
                    cv[k] = 0.f;
                    if (c < 4 * (k + 1)) {                // static prune
                        int r = l + 4 * k;
                        if (r > c) {
                            float v;
                            if (k == 0) { v = L0[LI0(c)] * rinv; L0[LI0(c)] = v; }
                            else if (k == 1) { v = L1[LI1(c)] * rinv; L1[LI1(c)] = v; }
                            else if (k == 2) { v = L2[LI2(c)] * rinv; L2[LI2(c)] = v; }
                            else { v = L3[c] * rinv; L3[c] = v; }
                            cv[k] = v;
                        }
                    }
                }
                #pragma unroll
                for (int j = c + 1; j < 16; ++j) {        // static j
                    float colj = __shfl(cv[j >> 2], lanebase + (j & 3), 64);
                    #pragma unroll
                    for (int k = 0; k < 4; ++k) {
                        if (j < 4 * (k + 1)) {            // static prune
                            int r = l + 4 * k;
                            if (r > j) {
                                float u = cv[k] * colj;
                                if (k == 0) L0[LI0(j)] -= u;
                                else if (k == 1) L1[LI1(j)] -= u;
                                else if (k == 2) L2[LI2(j)] -= u;
                                else L3[j] -= u;
                            } else if (r == j) {
                                dg[k] = fmaf(-colj, colj, dg[k]);
                            }
                        }
                    }
                }
            }

            // ---- Forward solve L y = kv ----
            float acc[4];
            #pragma unroll
            for (int k = 0; k < 4; ++k) acc[k] = kvown[k];
            float yown[4];
            #pragma unroll
            for (int r = 0; r < 16; ++r) {
                const int owner = r & 3, kr = r >> 2;     // static
                float yr = __shfl(acc[kr] * rinvown[kr], lanebase + owner, 64);
                if (l == owner) yown[kr] = yr;
                #pragma unroll
                for (int k = 0; k < 4; ++k) {
                    if (r < 4 * (k + 1)) {                // static prune
                        int rr = l + 4 * k;
                        if (rr > r) {
                            float lv;
                            if (k == 0) lv = L0[LI0(r)];
                            else if (k == 1) lv = L1[LI1(r)];
                            else if (k == 2) lv = L2[LI2(r)];
                            else lv = L3[r];
                            acc[k] = fmaf(-lv, yr, acc[k]);
                        }
                    }
                }
            }

            // ---- Backward solve L^T w = y ----
            float wfull[16];
            float wown[4] = {0.f, 0.f, 0.f, 0.f};
            #pragma unroll
            for (int r = 15; r >= 0; --r) {
                const int owner = r & 3, kr = r >> 2;     // static
                float contrib = 0.f;
                #pragma unroll
                for (int k = 0; k < 4; ++k) {
                    if (r < 4 * (k + 1)) {                // static prune
                        int j = l + 4 * k;
                        if (j > r) {
                            float lv;
                            if (k == 0) lv = L0[LI0(r)];
                            else if (k == 1) lv = L1[LI1(r)];
                            else if (k == 2) lv = L2[LI2(r)];
                            else lv = L3[r];
                            contrib = fmaf(lv, wown[k], contrib);
                        }
                    }
                }
                contrib += __shfl_xor(contrib, 1, 64);
                contrib += __shfl_xor(contrib, 2, 64);
                float wr = __shfl((yown[kr] - contrib) * rinvown[kr],
                                  lanebase + owner, 64);
                wfull[r] = wr;
                if (l == owner) wown[kr] = wr;
            }

            // ---- wk, ww, mean (owned + 2-shfl reduce) ----
            float wkp = 0.f, wwp = 0.f, mnp = 0.f;
            #pragma unroll
            for (int k = 0; k < 4; ++k) {
                wkp = fmaf(wown[k], kvown[k], wkp);
                wwp = fmaf(wown[k], wown[k], wwp);
                mnp = fmaf(wown[k], mus[iown[k]], mnp);
            }

            // ---- qs = w^T Su[idx,idx] w, rows split by ownership ----
            float qsp = 0.f;
            #pragma unroll
            for (int k = 0; k < 4; ++k) {
                int r = l + 4 * k;
                int a = iown[k];
                float wr = wown[k];
                float rowacc = 0.f;
                #pragma unroll
                for (int c = 0; c < 15; ++c) {            // static c
                    if (c < r) {
                        int bb2 = idx[c];
                        int hi = a > bb2 ? a : bb2;
                        int lo = a > bb2 ? bb2 : a;
                        rowacc = fmaf(wfull[c], P[((unsigned)hi * (hi + 1) >> 1) + lo], rowacc);
                    }
                }
                qsp = fmaf(wr, fmaf(wr, P[((unsigned)a * (a + 1) >> 1) + a], 2.0f * rowacc), qsp);
            }

            wkp += __shfl_xor(wkp, 1, 64); wkp += __shfl_xor(wkp, 2, 64);
            wwp += __shfl_xor(wwp, 1, 64); wwp += __shfl_xor(wwp, 2, 64);
            mnp += __shfl_xor(mnp, 1, 64); mnp += __shfl_xor(mnp, 2, 64);
            qsp += __shfl_xor(qsp, 1, 64); qsp += __shfl_xor(qsp, 2, 64);

            if (l == 0) {
                float cov = 1.0f - (wkp - JITTER * wwp) + qsp;
                float sd = sqrtf(fmaxf(cov, 0.05f));
                out[n] = mnp;
                out[N_PTS + n] = sd;
            }
        }
    }
}

// ---------------------------------------------------------------------------
extern "C" void kernel_launch(void* const* d_in, const int* in_sizes, int n_in,
                              void* d_out, int out_size, void* d_ws, size_t ws_size,
                              hipStream_t stream) {
    const float* X      = (const float*)d_in[0];
    const float* Z      = (const float*)d_in[1];
    const float* Lu_raw = (const float*)d_in[2];
    const float* mu     = (const float*)d_in[3];
    float* out = (float*)d_out;

    if (ws_size >= PACKED_BYTES + 64) {
        // Fused: P + completion counter live in d_ws.
        float* P = (float*)d_ws;
        unsigned int* ctr = (unsigned int*)((char*)d_ws + PACKED_BYTES);
        hipMemsetAsync(ctr, 0, sizeof(unsigned int), stream);
        vnngp_kernel<2><<<GRID_BLKS, 256, 0, stream>>>(X, Z, mu, P, Lu_raw, ctr, out);
    } else if (ws_size >= PACKED_BYTES) {
        float* P = (float*)d_ws;
        su_kernel<<<SU_BLOCKS, 256, 0, stream>>>(Lu_raw, P);
        vnngp_kernel<1><<<GRID_BLKS, 256, 0, stream>>>(X, Z, mu, P, Lu_raw, nullptr, out);
    } else {
        vnngp_kernel<0><<<GRID_BLKS, 256, 0, stream>>>(X, Z, mu, nullptr, Lu_raw, nullptr, out);
    }
}